// Round 3
// baseline (380.480 us; speedup 1.0000x reference)
//
#include <hip/hip_runtime.h>
#include <hip/hip_bf16.h>
#include <math.h>

#define HIDDEN 2048
#define EINTER 1024
#define NEXP 8
#define VOCAB 100000
#define TPE (VOCAB / NEXP)   // 12500

typedef unsigned short u16;
typedef __attribute__((ext_vector_type(8))) short short8;   // 8 bf16 (4 VGPRs)
typedef __attribute__((ext_vector_type(4))) float f32x4;

__device__ __forceinline__ u16 f2bf(float f) {
  union { float f; unsigned u; } v; v.f = f;
  unsigned r = v.u + 0x7fffu + ((v.u >> 16) & 1u);   // RNE, finite inputs only
  return (u16)(r >> 16);
}

__device__ __forceinline__ void gl2lds16(const u16* g, u16* l) {
  __builtin_amdgcn_global_load_lds(
      (const __attribute__((address_space(1))) unsigned int*)g,
      (__attribute__((address_space(3))) unsigned int*)l, 16, 0, 0);
}

// ---------------- routing ----------------
// hdr ints: [0..7]=cnt[e], [8..15]=off[e], [16]=n_tiles, [32..95]=worklist
__global__ void route_kernel(const int* __restrict__ ids, int T,
                             int* __restrict__ hdr, int* __restrict__ src_of) {
  __shared__ int cnt[NEXP], cur[NEXP];
  int tid = threadIdx.x;
  if (tid < NEXP) cnt[tid] = 0;
  __syncthreads();
  for (int t = tid; t < T; t += blockDim.x) {
    int id = ids[t]; id = min(max(id, 0), VOCAB - 1);
    int e = min(id / TPE, NEXP - 1);
    atomicAdd(&cnt[e], 1);
  }
  __syncthreads();
  if (tid == 0) {
    int acc = 0, nt = 0;
    for (int e = 0; e < NEXP; e++) {
      cur[e] = acc;
      hdr[e] = cnt[e];
      hdr[8 + e] = acc;
      int tiles = (cnt[e] + 127) >> 7;
      for (int m = 0; m < tiles; m++) hdr[32 + nt++] = (m << 3) | e;
      acc += cnt[e];
    }
    hdr[16] = nt;
  }
  __syncthreads();
  for (int t = tid; t < T; t += blockDim.x) {
    int id = ids[t]; id = min(max(id, 0), VOCAB - 1);
    int e = min(id / TPE, NEXP - 1);
    int pos = atomicAdd(&cur[e], 1);
    src_of[pos] = t;
  }
}

// ---------------- weight transpose + bf16 convert ----------------
// W [K][N] fp32 -> Wt [N][K] bf16. 128x128 tiles: 512B read rows, 256B write rows.
__global__ void prep_kernel(const float* __restrict__ gate, const float* __restrict__ up,
                            const float* __restrict__ down,
                            u16* __restrict__ gatet, u16* __restrict__ upt,
                            u16* __restrict__ downt) {
  int z = blockIdx.z, e = blockIdx.y;
  const float* W; u16* Wt; int K, N;
  if (z == 0)      { W = gate; Wt = gatet; K = 2048; N = 1024; }
  else if (z == 1) { W = up;   Wt = upt;   K = 2048; N = 1024; }
  else             { W = down; Wt = downt; K = 1024; N = 2048; }
  W  += (size_t)e * K * N;
  Wt += (size_t)e * K * N;
  int ntx = N >> 7;
  int tk = blockIdx.x / ntx, tn = blockIdx.x - tk * ntx;
  int k0 = tk << 7, n0 = tn << 7;

  __shared__ u16 tile[128][137];   // odd-ish stride: ~2-way both phases
  int t = threadIdx.x;
  int kr = t >> 5, cc = (t & 31) << 2;
  #pragma unroll
  for (int it = 0; it < 16; it++) {
    int kk = kr + (it << 3);
    float4 v = *(const float4*)(W + (size_t)(k0 + kk) * N + n0 + cc);
    tile[kk][cc]     = f2bf(v.x); tile[kk][cc + 1] = f2bf(v.y);
    tile[kk][cc + 2] = f2bf(v.z); tile[kk][cc + 3] = f2bf(v.w);
  }
  __syncthreads();
  #pragma unroll
  for (int it = 0; it < 8; it++) {
    int cid = (it << 8) + t;
    int nn = cid >> 4;           // 0..127
    int kc = (cid & 15) << 3;    // 0..120
    union { u16 s[8]; uint4 v; } o;
    #pragma unroll
    for (int j = 0; j < 8; j++) o.s[j] = tile[kc + j][nn];
    *(uint4*)(Wt + (size_t)(n0 + nn) * K + k0 + kc) = o.v;
  }
}

// ---------------- gather tokens -> bf16 rows ----------------
__global__ void gather_kernel(const float* __restrict__ x,
                              const int* __restrict__ src_of,
                              u16* __restrict__ Xg) {
  int p = blockIdx.x;
  int t = src_of[p];
  int c = threadIdx.x;
  const float4* src = (const float4*)(x + (size_t)t * HIDDEN) + c * 2;
  float4 a = src[0], b = src[1];
  union { u16 s[8]; uint4 v; } o;
  o.s[0] = f2bf(a.x); o.s[1] = f2bf(a.y); o.s[2] = f2bf(a.z); o.s[3] = f2bf(a.w);
  o.s[4] = f2bf(b.x); o.s[5] = f2bf(b.y); o.s[6] = f2bf(b.z); o.s[7] = f2bf(b.w);
  *((uint4*)(Xg + (size_t)p * HIDDEN) + c) = o.v;
}

// ---------------- gemm1: H = silu(Xg@Wg) * (Xg@Wu), fused, bf16 out ----------------
__launch_bounds__(256, 2)
__global__ void gemm1_kernel(const u16* __restrict__ Xg, const u16* __restrict__ gatet,
                             const u16* __restrict__ upt, u16* __restrict__ H,
                             const int* __restrict__ hdr, int T) {
  int ntile = hdr[16];
  if ((int)blockIdx.x >= ntile) return;
  int packed = hdr[32 + blockIdx.x];
  int e = packed & 7, mt = packed >> 3;
  int Me = hdr[e], base = hdr[8 + e];
  int row0 = base + (mt << 7);
  int valid = min(128, base + Me - row0);
  int n0 = blockIdx.y << 7;
  const u16* gbase = gatet + (size_t)e * (2048 * 1024);
  const u16* ubase = upt   + (size_t)e * (2048 * 1024);

  __shared__ u16 As[128][64];   // [m][k] 16 KB
  __shared__ u16 Bg[128][64];   // [n][k] 16 KB
  __shared__ u16 Bu[128][64];   // 16 KB

  int tid = threadIdx.x, lane = tid & 63, wv = tid >> 6;
  int wm = wv >> 1, wn = wv & 1;
  int quad = lane >> 4, ln = lane & 15;
  int srow = lane >> 3, schunk = lane & 7;

  f32x4 accG[4][4] = {};
  f32x4 accU[4][4] = {};

  for (int k0 = 0; k0 < 2048; k0 += 64) {
    __syncthreads();
    #pragma unroll
    for (int r = 0; r < 4; r++) {
      int c = (wv << 2) + r;                 // 0..15, 8 rows each
      int arow = (c << 3) + srow;
      int gr = min(row0 + arow, T - 1);      // clamped rows masked in epilogue
      gl2lds16(Xg + (size_t)gr * 2048 + k0 + (schunk << 3), &As[0][0] + (c << 9));
    }
    #pragma unroll
    for (int r = 0; r < 4; r++) {
      int c = (wv << 2) + r;
      int brow = (c << 3) + srow;
      gl2lds16(gbase + (size_t)(n0 + brow) * 2048 + k0 + (schunk << 3), &Bg[0][0] + (c << 9));
    }
    #pragma unroll
    for (int r = 0; r < 4; r++) {
      int c = (wv << 2) + r;
      int brow = (c << 3) + srow;
      gl2lds16(ubase + (size_t)(n0 + brow) * 2048 + k0 + (schunk << 3), &Bu[0][0] + (c << 9));
    }
    __syncthreads();
    #pragma unroll
    for (int s = 0; s < 2; s++) {
      short8 a[4], bg[4], bu[4];
      #pragma unroll
      for (int i = 0; i < 4; i++) {
        int m = (wm << 6) + (i << 4) + ln;
        a[i]  = *(const short8*)&As[m][(s << 5) + (quad << 3)];
        int n = (wn << 6) + (i << 4) + ln;
        bg[i] = *(const short8*)&Bg[n][(s << 5) + (quad << 3)];
        bu[i] = *(const short8*)&Bu[n][(s << 5) + (quad << 3)];
      }
      #pragma unroll
      for (int i = 0; i < 4; i++)
        #pragma unroll
        for (int j = 0; j < 4; j++) {
          accG[i][j] = __builtin_amdgcn_mfma_f32_16x16x32_bf16(a[i], bg[j], accG[i][j], 0, 0, 0);
          accU[i][j] = __builtin_amdgcn_mfma_f32_16x16x32_bf16(a[i], bu[j], accU[i][j], 0, 0, 0);
        }
    }
  }
  #pragma unroll
  for (int i = 0; i < 4; i++) {
    #pragma unroll
    for (int r = 0; r < 4; r++) {
      int rl = (wm << 6) + (i << 4) + (quad << 2) + r;
      if (rl < valid) {
        u16* orow = H + (size_t)(row0 + rl) * EINTER + n0 + (wn << 6) + ln;
        #pragma unroll
        for (int j = 0; j < 4; j++) {
          float g = accG[i][j][r], u = accU[i][j][r];
          orow[j << 4] = f2bf(g / (1.f + __expf(-g)) * u);
        }
      }
    }
  }
}

// ---------------- gemm2: out[src_of[p]] = H[p] @ down ----------------
__launch_bounds__(256, 3)
__global__ void gemm2_kernel(const u16* __restrict__ Hb, const u16* __restrict__ downt,
                             float* __restrict__ out, const int* __restrict__ src_of,
                             const int* __restrict__ hdr, int T) {
  int ntile = hdr[16];
  if ((int)blockIdx.x >= ntile) return;
  int packed = hdr[32 + blockIdx.x];
  int e = packed & 7, mt = packed >> 3;
  int Me = hdr[e], base = hdr[8 + e];
  int row0 = base + (mt << 7);
  int valid = min(128, base + Me - row0);
  int n0 = blockIdx.y << 7;
  const u16* wbase = downt + (size_t)e * (2048 * 1024);

  __shared__ u16 As[128][64];
  __shared__ u16 Bs[128][64];

  int tid = threadIdx.x, lane = tid & 63, wv = tid >> 6;
  int wm = wv >> 1, wn = wv & 1;
  int quad = lane >> 4, ln = lane & 15;
  int srow = lane >> 3, schunk = lane & 7;

  f32x4 acc[4][4] = {};

  for (int k0 = 0; k0 < 1024; k0 += 64) {
    __syncthreads();
    #pragma unroll
    for (int r = 0; r < 4; r++) {
      int c = (wv << 2) + r;
      int arow = (c << 3) + srow;
      int gr = min(row0 + arow, T - 1);
      gl2lds16(Hb + (size_t)gr * 1024 + k0 + (schunk << 3), &As[0][0] + (c << 9));
    }
    #pragma unroll
    for (int r = 0; r < 4; r++) {
      int c = (wv << 2) + r;
      int brow = (c << 3) + srow;
      gl2lds16(wbase + (size_t)(n0 + brow) * 1024 + k0 + (schunk << 3), &Bs[0][0] + (c << 9));
    }
    __syncthreads();
    #pragma unroll
    for (int s = 0; s < 2; s++) {
      short8 a[4], b[4];
      #pragma unroll
      for (int i = 0; i < 4; i++) {
        int m = (wm << 6) + (i << 4) + ln;
        a[i] = *(const short8*)&As[m][(s << 5) + (quad << 3)];
        int n = (wn << 6) + (i << 4) + ln;
        b[i] = *(const short8*)&Bs[n][(s << 5) + (quad << 3)];
      }
      #pragma unroll
      for (int i = 0; i < 4; i++)
        #pragma unroll
        for (int j = 0; j < 4; j++)
          acc[i][j] = __builtin_amdgcn_mfma_f32_16x16x32_bf16(a[i], b[j], acc[i][j], 0, 0, 0);
    }
  }
  #pragma unroll
  for (int i = 0; i < 4; i++) {
    #pragma unroll
    for (int r = 0; r < 4; r++) {
      int rl = (wm << 6) + (i << 4) + (quad << 2) + r;
      if (rl < valid) {
        int t = src_of[row0 + rl];
        float* orow = out + (size_t)t * HIDDEN + n0 + (wn << 6) + ln;
        #pragma unroll
        for (int j = 0; j < 4; j++) orow[j << 4] = acc[i][j][r];
      }
    }
  }
}

extern "C" void kernel_launch(void* const* d_in, const int* in_sizes, int n_in,
                              void* d_out, int out_size, void* d_ws, size_t ws_size,
                              hipStream_t stream) {
  const float* x    = (const float*)d_in[0];
  const int*   ids  = (const int*)d_in[1];
  const float* gate = (const float*)d_in[2];
  const float* up   = (const float*)d_in[3];
  const float* down = (const float*)d_in[4];
  float* out = (float*)d_out;

  int T = in_sizes[0] / HIDDEN;              // 4096

  char* w = (char*)d_ws;
  int* hdr    = (int*)w;                                   // 1 KB
  int* src_of = (int*)(w + 1024);
  size_t off = 1024 + (size_t)T * 4;
  u16* Xg   = (u16*)(w + off);  off += (size_t)T * HIDDEN * 2;
  u16* Hb   = (u16*)(w + off);  off += (size_t)T * EINTER * 2;
  u16* gatet = (u16*)(w + off); off += (size_t)NEXP * HIDDEN * EINTER * 2;
  u16* upt   = (u16*)(w + off); off += (size_t)NEXP * HIDDEN * EINTER * 2;
  u16* downt = (u16*)(w + off); off += (size_t)NEXP * HIDDEN * EINTER * 2;

  int maxt = (T + 127) / 128 + (NEXP - 1) + 1;   // 40 worst-case tiles

  prep_kernel<<<dim3(128, NEXP, 3), 256, 0, stream>>>(gate, up, down, gatet, upt, downt);
  route_kernel<<<1, 256, 0, stream>>>(ids, T, hdr, src_of);
  gather_kernel<<<T, 256, 0, stream>>>(x, src_of, Xg);
  gemm1_kernel<<<dim3(maxt, EINTER / 128), 256, 0, stream>>>(Xg, gatet, upt, Hb, hdr, T);
  gemm2_kernel<<<dim3(maxt, HIDDEN / 128), 256, 0, stream>>>(Hb, downt, out, src_of, hdr, T);
}

// Round 4
// 361.587 us; speedup vs baseline: 1.0523x; 1.0523x over previous
//
#include <hip/hip_runtime.h>
#include <hip/hip_bf16.h>
#include <math.h>

#define HIDDEN 2048
#define EINTER 1024
#define NEXP 8
#define VOCAB 100000
#define TPE (VOCAB / NEXP)   // 12500

typedef unsigned short u16;
typedef __attribute__((ext_vector_type(8))) short short8;   // 8 bf16 (4 VGPRs)
typedef __attribute__((ext_vector_type(4))) float f32x4;

__device__ __forceinline__ u16 f2bf(float f) {
  union { float f; unsigned u; } v; v.f = f;
  unsigned r = v.u + 0x7fffu + ((v.u >> 16) & 1u);   // RNE, finite inputs only
  return (u16)(r >> 16);
}

__device__ __forceinline__ void gl2lds16(const u16* g, u16* l) {
  __builtin_amdgcn_global_load_lds(
      (const __attribute__((address_space(1))) unsigned int*)g,
      (__attribute__((address_space(3))) unsigned int*)l, 16, 0, 0);
}

// ---------------- routing ----------------
// hdr ints: [0..7]=cnt[e], [8..15]=off[e], [16]=n_tiles, [32..95]=worklist
__global__ void route_kernel(const int* __restrict__ ids, int T,
                             int* __restrict__ hdr, int* __restrict__ src_of) {
  __shared__ int cnt[NEXP], cur[NEXP];
  int tid = threadIdx.x;
  if (tid < NEXP) cnt[tid] = 0;
  __syncthreads();
  for (int t = tid; t < T; t += blockDim.x) {
    int id = ids[t]; id = min(max(id, 0), VOCAB - 1);
    int e = min(id / TPE, NEXP - 1);
    atomicAdd(&cnt[e], 1);
  }
  __syncthreads();
  if (tid == 0) {
    int acc = 0, nt = 0;
    for (int e = 0; e < NEXP; e++) {
      cur[e] = acc;
      hdr[e] = cnt[e];
      hdr[8 + e] = acc;
      int tiles = (cnt[e] + 127) >> 7;
      for (int m = 0; m < tiles; m++) hdr[32 + nt++] = (m << 3) | e;
      acc += cnt[e];
    }
    hdr[16] = nt;
  }
  __syncthreads();
  for (int t = tid; t < T; t += blockDim.x) {
    int id = ids[t]; id = min(max(id, 0), VOCAB - 1);
    int e = min(id / TPE, NEXP - 1);
    int pos = atomicAdd(&cur[e], 1);
    src_of[pos] = t;
  }
}

// ---------------- weight prep: fp32 [K][N] -> bf16 tiled [n_blk128][k_blk64] tiles ----------------
// Each tile is 128n x 64k row-major (the GEMM LDS image). Block covers 128k x 128n
// -> writes two tiles = 32 KB FULLY SEQUENTIAL.
__global__ void prep_kernel(const float* __restrict__ gate, const float* __restrict__ up,
                            const float* __restrict__ down,
                            u16* __restrict__ gatet, u16* __restrict__ upt,
                            u16* __restrict__ downt) {
  int z = blockIdx.z, e = blockIdx.y;
  const float* W; u16* Wt; int K, N;
  if (z == 0)      { W = gate; Wt = gatet; K = 2048; N = 1024; }
  else if (z == 1) { W = up;   Wt = upt;   K = 2048; N = 1024; }
  else             { W = down; Wt = downt; K = 1024; N = 2048; }
  W += (size_t)e * K * N;
  int ntx = N >> 7;
  int tk = blockIdx.x / ntx, tn = blockIdx.x - tk * ntx;
  int k0 = tk << 7, n0 = tn << 7;
  int kblks = K >> 6;
  // output base: tiles ordered [e][n_blk][k_blk], each 8192 u16
  u16* obase = Wt + ((size_t)(((size_t)e * ntx + tn) * kblks + (tk << 1))) * 8192
                  + (size_t)e * 0;  // e folded above via ntx*kblks*... careful below
  // NOTE: e-term must scale by full expert size:
  obase = Wt + (size_t)e * ((size_t)K * N)
             + ((size_t)tn * kblks + (tk << 1)) * 8192;

  __shared__ u16 tile[128][130];   // row stride 260B == 65 banks -> <=2-way everywhere
  int t = threadIdx.x;
  int kr = t >> 5, cc = (t & 31) << 2;
  #pragma unroll
  for (int it = 0; it < 16; it++) {
    int kk = kr + (it << 3);
    float4 v = *(const float4*)(W + (size_t)(k0 + kk) * N + n0 + cc);
    tile[kk][cc]     = f2bf(v.x); tile[kk][cc + 1] = f2bf(v.y);
    tile[kk][cc + 2] = f2bf(v.z); tile[kk][cc + 3] = f2bf(v.w);
  }
  __syncthreads();
  #pragma unroll
  for (int it = 0; it < 8; it++) {
    int cid = (it << 8) + t;            // 0..2047 uint4s = 32 KB
    int ti  = cid >> 10;                // which 64k-tile (0,1)
    int idx = cid & 1023;
    int nn  = idx >> 3;                 // 0..127
    int kc  = (ti << 6) + ((idx & 7) << 3);
    union { u16 s[8]; uint4 v; } o;
    #pragma unroll
    for (int j = 0; j < 8; j++) o.s[j] = tile[kc + j][nn];
    *((uint4*)obase + cid) = o.v;       // fully sequential block write
  }
}

// ---------------- gather tokens -> bf16 rows ----------------
__global__ void gather_kernel(const float* __restrict__ x,
                              const int* __restrict__ src_of,
                              u16* __restrict__ Xg) {
  int p = blockIdx.x;
  int t = src_of[p];
  int c = threadIdx.x;
  const float4* src = (const float4*)(x + (size_t)t * HIDDEN) + c * 2;
  float4 a = src[0], b = src[1];
  union { u16 s[8]; uint4 v; } o;
  o.s[0] = f2bf(a.x); o.s[1] = f2bf(a.y); o.s[2] = f2bf(a.z); o.s[3] = f2bf(a.w);
  o.s[4] = f2bf(b.x); o.s[5] = f2bf(b.y); o.s[6] = f2bf(b.z); o.s[7] = f2bf(b.w);
  *((uint4*)(Xg + (size_t)p * HIDDEN) + c) = o.v;
}

// ---------------- gemm1: H = silu(Xg@Wg) * (Xg@Wu), 128m x 64n tiles ----------------
__launch_bounds__(256, 3)
__global__ void gemm1_kernel(const u16* __restrict__ Xg, const u16* __restrict__ gatet,
                             const u16* __restrict__ upt, u16* __restrict__ H,
                             const int* __restrict__ hdr, int T) {
  int ntile = hdr[16];
  if ((int)blockIdx.x >= ntile) return;
  int packed = hdr[32 + blockIdx.x];
  int e = packed & 7, mt = packed >> 3;
  int Me = hdr[e], base = hdr[8 + e];
  int row0 = base + (mt << 7);
  int valid = min(128, base + Me - row0);
  int n0 = blockIdx.y << 6;                          // 0..960
  size_t ebase = (size_t)e * (2048 * 1024);
  size_t tbase = ((size_t)(n0 >> 7) * 32) * 8192 + (size_t)((n0 >> 6) & 1) * 4096;
  const u16* gW = gatet + ebase + tbase;
  const u16* uW = upt   + ebase + tbase;

  __shared__ u16 As[128][64];   // 16 KB
  __shared__ u16 Bg[64][64];    // 8 KB
  __shared__ u16 Bu[64][64];    // 8 KB

  int tid = threadIdx.x, lane = tid & 63, wv = tid >> 6;
  int wm = wv >> 1, wn = wv & 1;
  int quad = lane >> 4, ln = lane & 15;

  f32x4 accG[4][2] = {};
  f32x4 accU[4][2] = {};

  for (int k0 = 0; k0 < 2048; k0 += 64) {
    size_t woff = (size_t)(k0 >> 6) * 8192 + lane * 8;
    __syncthreads();
    #pragma unroll
    for (int r = 0; r < 4; r++) {
      int c = (wv << 2) + r;                 // 16 chunks of 8 rows
      int arow = (c << 3) + (lane >> 3);
      int gr = min(row0 + arow, T - 1);      // clamped rows masked in epilogue
      gl2lds16(Xg + (size_t)gr * 2048 + k0 + ((lane & 7) << 3), &As[0][0] + (c << 9));
    }
    #pragma unroll
    for (int r = 0; r < 2; r++) {
      int c = (wv << 1) + r;                 // 8 chunks, contiguous 1KB/wave
      gl2lds16(gW + woff + (c << 9), &Bg[0][0] + (c << 9));
    }
    #pragma unroll
    for (int r = 0; r < 2; r++) {
      int c = (wv << 1) + r;
      gl2lds16(uW + woff + (c << 9), &Bu[0][0] + (c << 9));
    }
    __syncthreads();
    #pragma unroll
    for (int s = 0; s < 2; s++) {
      short8 a[4], bg[2], bu[2];
      #pragma unroll
      for (int i = 0; i < 4; i++) {
        int m = (wm << 6) + (i << 4) + ln;
        a[i] = *(const short8*)&As[m][(s << 5) + (quad << 3)];
      }
      #pragma unroll
      for (int j = 0; j < 2; j++) {
        int n = (wn << 5) + (j << 4) + ln;
        bg[j] = *(const short8*)&Bg[n][(s << 5) + (quad << 3)];
        bu[j] = *(const short8*)&Bu[n][(s << 5) + (quad << 3)];
      }
      #pragma unroll
      for (int i = 0; i < 4; i++)
        #pragma unroll
        for (int j = 0; j < 2; j++) {
          accG[i][j] = __builtin_amdgcn_mfma_f32_16x16x32_bf16(a[i], bg[j], accG[i][j], 0, 0, 0);
          accU[i][j] = __builtin_amdgcn_mfma_f32_16x16x32_bf16(a[i], bu[j], accU[i][j], 0, 0, 0);
        }
    }
  }
  #pragma unroll
  for (int i = 0; i < 4; i++) {
    #pragma unroll
    for (int r = 0; r < 4; r++) {
      int rl = (wm << 6) + (i << 4) + (quad << 2) + r;
      if (rl < valid) {
        u16* orow = H + (size_t)(row0 + rl) * EINTER + n0 + (wn << 5) + ln;
        #pragma unroll
        for (int j = 0; j < 2; j++) {
          float g = accG[i][j][r], u = accU[i][j][r];
          orow[j << 4] = f2bf(g / (1.f + __expf(-g)) * u);
        }
      }
    }
  }
}

// ---------------- gemm2: out[src_of[p]] = H[p] @ down, 128x128 ----------------
__launch_bounds__(256, 4)
__global__ void gemm2_kernel(const u16* __restrict__ Hb, const u16* __restrict__ downt,
                             float* __restrict__ out, const int* __restrict__ src_of,
                             const int* __restrict__ hdr, int T) {
  int ntile = hdr[16];
  if ((int)blockIdx.x >= ntile) return;
  int packed = hdr[32 + blockIdx.x];
  int e = packed & 7, mt = packed >> 3;
  int Me = hdr[e], base = hdr[8 + e];
  int row0 = base + (mt << 7);
  int valid = min(128, base + Me - row0);
  int n0 = blockIdx.y << 7;
  const u16* wbase = downt + (size_t)e * (2048 * 1024)
                   + ((size_t)(n0 >> 7) * 16) * 8192;

  __shared__ u16 As[128][64];
  __shared__ u16 Bs[128][64];

  int tid = threadIdx.x, lane = tid & 63, wv = tid >> 6;
  int wm = wv >> 1, wn = wv & 1;
  int quad = lane >> 4, ln = lane & 15;

  f32x4 acc[4][4] = {};

  for (int k0 = 0; k0 < 1024; k0 += 64) {
    size_t woff = (size_t)(k0 >> 6) * 8192 + lane * 8;
    __syncthreads();
    #pragma unroll
    for (int r = 0; r < 4; r++) {
      int c = (wv << 2) + r;
      int arow = (c << 3) + (lane >> 3);
      int gr = min(row0 + arow, T - 1);
      gl2lds16(Hb + (size_t)gr * 1024 + k0 + ((lane & 7) << 3), &As[0][0] + (c << 9));
    }
    #pragma unroll
    for (int r = 0; r < 4; r++) {
      int c = (wv << 2) + r;
      gl2lds16(wbase + woff + (c << 9), &Bs[0][0] + (c << 9));
    }
    __syncthreads();
    #pragma unroll
    for (int s = 0; s < 2; s++) {
      short8 a[4], b[4];
      #pragma unroll
      for (int i = 0; i < 4; i++) {
        int m = (wm << 6) + (i << 4) + ln;
        a[i] = *(const short8*)&As[m][(s << 5) + (quad << 3)];
        int n = (wn << 6) + (i << 4) + ln;
        b[i] = *(const short8*)&Bs[n][(s << 5) + (quad << 3)];
      }
      #pragma unroll
      for (int i = 0; i < 4; i++)
        #pragma unroll
        for (int j = 0; j < 4; j++)
          acc[i][j] = __builtin_amdgcn_mfma_f32_16x16x32_bf16(a[i], b[j], acc[i][j], 0, 0, 0);
    }
  }
  #pragma unroll
  for (int i = 0; i < 4; i++) {
    #pragma unroll
    for (int r = 0; r < 4; r++) {
      int rl = (wm << 6) + (i << 4) + (quad << 2) + r;
      if (rl < valid) {
        int t = src_of[row0 + rl];
        float* orow = out + (size_t)t * HIDDEN + n0 + (wn << 6) + ln;
        #pragma unroll
        for (int j = 0; j < 4; j++) orow[j << 4] = acc[i][j][r];
      }
    }
  }
}

extern "C" void kernel_launch(void* const* d_in, const int* in_sizes, int n_in,
                              void* d_out, int out_size, void* d_ws, size_t ws_size,
                              hipStream_t stream) {
  const float* x    = (const float*)d_in[0];
  const int*   ids  = (const int*)d_in[1];
  const float* gate = (const float*)d_in[2];
  const float* up   = (const float*)d_in[3];
  const float* down = (const float*)d_in[4];
  float* out = (float*)d_out;

  int T = in_sizes[0] / HIDDEN;              // 4096

  char* w = (char*)d_ws;
  int* hdr    = (int*)w;                                   // 1 KB
  int* src_of = (int*)(w + 1024);
  size_t off = 1024 + (size_t)T * 4;
  u16* Xg   = (u16*)(w + off);  off += (size_t)T * HIDDEN * 2;
  u16* Hb   = (u16*)(w + off);  off += (size_t)T * EINTER * 2;
  u16* gatet = (u16*)(w + off); off += (size_t)NEXP * HIDDEN * EINTER * 2;
  u16* upt   = (u16*)(w + off); off += (size_t)NEXP * HIDDEN * EINTER * 2;
  u16* downt = (u16*)(w + off); off += (size_t)NEXP * HIDDEN * EINTER * 2;

  int maxt = (T + 127) / 128 + (NEXP - 1) + 1;   // 40 worst-case tiles

  prep_kernel<<<dim3(128, NEXP, 3), 256, 0, stream>>>(gate, up, down, gatet, upt, downt);
  route_kernel<<<1, 256, 0, stream>>>(ids, T, hdr, src_of);
  gather_kernel<<<T, 256, 0, stream>>>(x, src_of, Xg);
  gemm1_kernel<<<dim3(maxt, EINTER / 64), 256, 0, stream>>>(Xg, gatet, upt, Hb, hdr, T);
  gemm2_kernel<<<dim3(maxt, HIDDEN / 128), 256, 0, stream>>>(Hb, downt, out, src_of, hdr, T);
}

// Round 5
// 357.476 us; speedup vs baseline: 1.0644x; 1.0115x over previous
//
#include <hip/hip_runtime.h>
#include <hip/hip_bf16.h>
#include <math.h>

#define HIDDEN 2048
#define EINTER 1024
#define NEXP 8
#define VOCAB 100000
#define TPE (VOCAB / NEXP)   // 12500

typedef unsigned short u16;
typedef __attribute__((ext_vector_type(8))) short short8;   // 8 bf16 (4 VGPRs)
typedef __attribute__((ext_vector_type(4))) float f32x4;

__device__ __forceinline__ u16 f2bf(float f) {
  union { float f; unsigned u; } v; v.f = f;
  unsigned r = v.u + 0x7fffu + ((v.u >> 16) & 1u);   // RNE, finite inputs only
  return (u16)(r >> 16);
}

__device__ __forceinline__ float f4get(const float4& a, int i) {
  return i == 0 ? a.x : i == 1 ? a.y : i == 2 ? a.z : a.w;
}

__device__ __forceinline__ void gl2lds16(const u16* g, u16* l) {
  __builtin_amdgcn_global_load_lds(
      (const __attribute__((address_space(1))) unsigned int*)g,
      (__attribute__((address_space(3))) unsigned int*)l, 16, 0, 0);
}

// ---------------- routing ----------------
// hdr ints: [0..7]=cnt[e], [8..15]=off[e], [16]=n_tiles, [32..95]=worklist
__global__ void route_kernel(const int* __restrict__ ids, int T,
                             int* __restrict__ hdr, int* __restrict__ src_of) {
  __shared__ int cnt[NEXP], cur[NEXP];
  int tid = threadIdx.x;
  if (tid < NEXP) cnt[tid] = 0;
  __syncthreads();
  for (int t = tid; t < T; t += blockDim.x) {
    int id = ids[t]; id = min(max(id, 0), VOCAB - 1);
    int e = min(id / TPE, NEXP - 1);
    atomicAdd(&cnt[e], 1);
  }
  __syncthreads();
  if (tid == 0) {
    int acc = 0, nt = 0;
    for (int e = 0; e < NEXP; e++) {
      cur[e] = acc;
      hdr[e] = cnt[e];
      hdr[8 + e] = acc;
      int tiles = (cnt[e] + 127) >> 7;
      for (int m = 0; m < tiles; m++) hdr[32 + nt++] = (m << 3) | e;
      acc += cnt[e];
    }
    hdr[16] = nt;
  }
  __syncthreads();
  for (int t = tid; t < T; t += blockDim.x) {
    int id = ids[t]; id = min(max(id, 0), VOCAB - 1);
    int e = min(id / TPE, NEXP - 1);
    int pos = atomicAdd(&cur[e], 1);
    src_of[pos] = t;
  }
}

// ---------------- weight prep: fp32 [K][N] -> bf16 tiles [e][n_blk128][k_blk64] ----------------
// Register 4x4 transpose + XOR-swizzled LDS (b64 writes / b128 reads, no pad).
__global__ void prep_kernel(const float* __restrict__ gate, const float* __restrict__ up,
                            const float* __restrict__ down,
                            u16* __restrict__ gatet, u16* __restrict__ upt,
                            u16* __restrict__ downt) {
  int z = blockIdx.z, e = blockIdx.y;
  const float* W; u16* Wt; int K, N;
  if (z == 0)      { W = gate; Wt = gatet; K = 2048; N = 1024; }
  else if (z == 1) { W = up;   Wt = upt;   K = 2048; N = 1024; }
  else             { W = down; Wt = downt; K = 1024; N = 2048; }
  W += (size_t)e * K * N;
  int ntx = N >> 7;
  int tk = blockIdx.x / ntx, tn = blockIdx.x - tk * ntx;
  int k0 = tk << 7, n0 = tn << 7;
  // tile order [e][n_blk][k_blk], each 64k x 128n tile = 8192 u16 = 1024 uint4
  size_t tile0 = ((size_t)e * ntx + tn) * (size_t)(K >> 6) + ((size_t)tk << 1);
  uint4* ob = (uint4*)Wt + tile0 * 1024;

  __shared__ u16 Ts[128 * 128];   // [n][k] swizzled, 32 KB, no pad
  int t = threadIdx.x;
  int kkb = (t >> 5) << 2;        // 0..28
  int cc  = (t & 31) << 2;        // 0..124 (n)

  // phase 1: hoisted loads (MLP), register transpose, b64 LDS writes
  float4 v[4][4];
  const float* Wb = W + (size_t)k0 * N + n0 + cc;
  #pragma unroll
  for (int r = 0; r < 4; r++)
    #pragma unroll
    for (int i = 0; i < 4; i++)
      v[r][i] = *(const float4*)(Wb + (size_t)(kkb + (r << 5) + i) * N);

  #pragma unroll
  for (int r = 0; r < 4; r++) {
    int kk = kkb + (r << 5);
    int cbase = kk >> 3, klo = kk & 7;
    #pragma unroll
    for (int i2 = 0; i2 < 4; i2++) {
      int n_loc = cc + i2;
      int cp = cbase ^ ((n_loc >> 2) & 15);
      unsigned lo = (unsigned)f2bf(f4get(v[r][0], i2)) | ((unsigned)f2bf(f4get(v[r][1], i2)) << 16);
      unsigned hi = (unsigned)f2bf(f4get(v[r][2], i2)) | ((unsigned)f2bf(f4get(v[r][3], i2)) << 16);
      uint2 pk; pk.x = lo; pk.y = hi;
      *(uint2*)&Ts[n_loc * 128 + (cp << 3) + klo] = pk;
    }
  }
  __syncthreads();
  // phase 2: b128 LDS reads (de-swizzle), tiled global writes (128B segments)
  #pragma unroll
  for (int it = 0; it < 8; it++) {
    int cid = (it << 8) + t;        // 0..2047
    int n_loc = cid >> 4, p = cid & 15;
    int cp = p ^ ((n_loc >> 2) & 15);
    uint4 val = *(const uint4*)&Ts[n_loc * 128 + (cp << 3)];
    int kt = p >> 3;
    ob[((size_t)kt << 10) + (n_loc << 3) + (p & 7)] = val;
  }
}

// ---------------- gather tokens -> bf16 rows ----------------
__global__ void gather_kernel(const float* __restrict__ x,
                              const int* __restrict__ src_of,
                              u16* __restrict__ Xg) {
  int p = blockIdx.x;
  int t = src_of[p];
  int c = threadIdx.x;
  const float4* src = (const float4*)(x + (size_t)t * HIDDEN) + c * 2;
  float4 a = src[0], b = src[1];
  union { u16 s[8]; uint4 v; } o;
  o.s[0] = f2bf(a.x); o.s[1] = f2bf(a.y); o.s[2] = f2bf(a.z); o.s[3] = f2bf(a.w);
  o.s[4] = f2bf(b.x); o.s[5] = f2bf(b.y); o.s[6] = f2bf(b.z); o.s[7] = f2bf(b.w);
  *((uint4*)(Xg + (size_t)p * HIDDEN) + c) = o.v;
}

// ---------------- gemm1: H = silu(Xg@Wg) * (Xg@Wu), 128m x 64n tiles ----------------
__launch_bounds__(256, 3)
__global__ void gemm1_kernel(const u16* __restrict__ Xg, const u16* __restrict__ gatet,
                             const u16* __restrict__ upt, u16* __restrict__ H,
                             const int* __restrict__ hdr, int T) {
  int ntile = hdr[16];
  if ((int)blockIdx.x >= ntile) return;
  int packed = hdr[32 + blockIdx.x];
  int e = packed & 7, mt = packed >> 3;
  int Me = hdr[e], base = hdr[8 + e];
  int row0 = base + (mt << 7);
  int valid = min(128, base + Me - row0);
  int n0 = blockIdx.y << 6;                          // 0..960
  size_t ebase = (size_t)e * (2048 * 1024);
  size_t tbase = ((size_t)(n0 >> 7) * 32) * 8192 + (size_t)((n0 >> 6) & 1) * 4096;
  const u16* gW = gatet + ebase + tbase;
  const u16* uW = upt   + ebase + tbase;

  __shared__ u16 As[128][64];   // 16 KB
  __shared__ u16 Bg[64][64];    // 8 KB
  __shared__ u16 Bu[64][64];    // 8 KB

  int tid = threadIdx.x, lane = tid & 63, wv = tid >> 6;
  int wm = wv >> 1, wn = wv & 1;
  int quad = lane >> 4, ln = lane & 15;

  f32x4 accG[4][2] = {};
  f32x4 accU[4][2] = {};

  for (int k0 = 0; k0 < 2048; k0 += 64) {
    size_t woff = (size_t)(k0 >> 6) * 8192 + lane * 8;
    __syncthreads();
    #pragma unroll
    for (int r = 0; r < 4; r++) {
      int c = (wv << 2) + r;                 // 16 chunks of 8 rows
      int arow = (c << 3) + (lane >> 3);
      int gr = min(row0 + arow, T - 1);      // clamped rows masked in epilogue
      gl2lds16(Xg + (size_t)gr * 2048 + k0 + ((lane & 7) << 3), &As[0][0] + (c << 9));
    }
    #pragma unroll
    for (int r = 0; r < 2; r++) {
      int c = (wv << 1) + r;                 // 8 chunks, contiguous 1KB/wave
      gl2lds16(gW + woff + (c << 9), &Bg[0][0] + (c << 9));
    }
    #pragma unroll
    for (int r = 0; r < 2; r++) {
      int c = (wv << 1) + r;
      gl2lds16(uW + woff + (c << 9), &Bu[0][0] + (c << 9));
    }
    __syncthreads();
    #pragma unroll
    for (int s = 0; s < 2; s++) {
      short8 a[4], bg[2], bu[2];
      #pragma unroll
      for (int i = 0; i < 4; i++) {
        int m = (wm << 6) + (i << 4) + ln;
        a[i] = *(const short8*)&As[m][(s << 5) + (quad << 3)];
      }
      #pragma unroll
      for (int j = 0; j < 2; j++) {
        int n = (wn << 5) + (j << 4) + ln;
        bg[j] = *(const short8*)&Bg[n][(s << 5) + (quad << 3)];
        bu[j] = *(const short8*)&Bu[n][(s << 5) + (quad << 3)];
      }
      #pragma unroll
      for (int i = 0; i < 4; i++)
        #pragma unroll
        for (int j = 0; j < 2; j++) {
          accG[i][j] = __builtin_amdgcn_mfma_f32_16x16x32_bf16(a[i], bg[j], accG[i][j], 0, 0, 0);
          accU[i][j] = __builtin_amdgcn_mfma_f32_16x16x32_bf16(a[i], bu[j], accU[i][j], 0, 0, 0);
        }
    }
  }
  #pragma unroll
  for (int i = 0; i < 4; i++) {
    #pragma unroll
    for (int r = 0; r < 4; r++) {
      int rl = (wm << 6) + (i << 4) + (quad << 2) + r;
      if (rl < valid) {
        u16* orow = H + (size_t)(row0 + rl) * EINTER + n0 + (wn << 5) + ln;
        #pragma unroll
        for (int j = 0; j < 2; j++) {
          float g = accG[i][j][r], u = accU[i][j][r];
          orow[j << 4] = f2bf(g / (1.f + __expf(-g)) * u);
        }
      }
    }
  }
}

// ---------------- gemm2: out[src_of[p]] = H[p] @ down, 128x128 ----------------
__launch_bounds__(256, 4)
__global__ void gemm2_kernel(const u16* __restrict__ Hb, const u16* __restrict__ downt,
                             float* __restrict__ out, const int* __restrict__ src_of,
                             const int* __restrict__ hdr, int T) {
  int ntile = hdr[16];
  if ((int)blockIdx.x >= ntile) return;
  int packed = hdr[32 + blockIdx.x];
  int e = packed & 7, mt = packed >> 3;
  int Me = hdr[e], base = hdr[8 + e];
  int row0 = base + (mt << 7);
  int valid = min(128, base + Me - row0);
  int n0 = blockIdx.y << 7;
  const u16* wbase = downt + (size_t)e * (2048 * 1024)
                   + ((size_t)(n0 >> 7) * 16) * 8192;

  __shared__ u16 As[128][64];
  __shared__ u16 Bs[128][64];

  int tid = threadIdx.x, lane = tid & 63, wv = tid >> 6;
  int wm = wv >> 1, wn = wv & 1;
  int quad = lane >> 4, ln = lane & 15;

  f32x4 acc[4][4] = {};

  for (int k0 = 0; k0 < 1024; k0 += 64) {
    size_t woff = (size_t)(k0 >> 6) * 8192 + lane * 8;
    __syncthreads();
    #pragma unroll
    for (int r = 0; r < 4; r++) {
      int c = (wv << 2) + r;
      int arow = (c << 3) + (lane >> 3);
      int gr = min(row0 + arow, T - 1);
      gl2lds16(Hb + (size_t)gr * 1024 + k0 + ((lane & 7) << 3), &As[0][0] + (c << 9));
    }
    #pragma unroll
    for (int r = 0; r < 4; r++) {
      int c = (wv << 2) + r;
      gl2lds16(wbase + woff + (c << 9), &Bs[0][0] + (c << 9));
    }
    __syncthreads();
    #pragma unroll
    for (int s = 0; s < 2; s++) {
      short8 a[4], b[4];
      #pragma unroll
      for (int i = 0; i < 4; i++) {
        int m = (wm << 6) + (i << 4) + ln;
        a[i] = *(const short8*)&As[m][(s << 5) + (quad << 3)];
        int n = (wn << 6) + (i << 4) + ln;
        b[i] = *(const short8*)&Bs[n][(s << 5) + (quad << 3)];
      }
      #pragma unroll
      for (int i = 0; i < 4; i++)
        #pragma unroll
        for (int j = 0; j < 4; j++)
          acc[i][j] = __builtin_amdgcn_mfma_f32_16x16x32_bf16(a[i], b[j], acc[i][j], 0, 0, 0);
    }
  }
  #pragma unroll
  for (int i = 0; i < 4; i++) {
    #pragma unroll
    for (int r = 0; r < 4; r++) {
      int rl = (wm << 6) + (i << 4) + (quad << 2) + r;
      if (rl < valid) {
        int t = src_of[row0 + rl];
        float* orow = out + (size_t)t * HIDDEN + n0 + (wn << 6) + ln;
        #pragma unroll
        for (int j = 0; j < 4; j++) orow[j << 4] = acc[i][j][r];
      }
    }
  }
}

extern "C" void kernel_launch(void* const* d_in, const int* in_sizes, int n_in,
                              void* d_out, int out_size, void* d_ws, size_t ws_size,
                              hipStream_t stream) {
  const float* x    = (const float*)d_in[0];
  const int*   ids  = (const int*)d_in[1];
  const float* gate = (const float*)d_in[2];
  const float* up   = (const float*)d_in[3];
  const float* down = (const float*)d_in[4];
  float* out = (float*)d_out;

  int T = in_sizes[0] / HIDDEN;              // 4096

  char* w = (char*)d_ws;
  int* hdr    = (int*)w;                                   // 1 KB
  int* src_of = (int*)(w + 1024);
  size_t off = 1024 + (size_t)T * 4;
  u16* Xg   = (u16*)(w + off);  off += (size_t)T * HIDDEN * 2;
  u16* Hb   = (u16*)(w + off);  off += (size_t)T * EINTER * 2;
  u16* gatet = (u16*)(w + off); off += (size_t)NEXP * HIDDEN * EINTER * 2;
  u16* upt   = (u16*)(w + off); off += (size_t)NEXP * HIDDEN * EINTER * 2;
  u16* downt = (u16*)(w + off); off += (size_t)NEXP * HIDDEN * EINTER * 2;

  int maxt = (T + 127) / 128 + (NEXP - 1) + 1;   // 40 worst-case tiles

  prep_kernel<<<dim3(128, NEXP, 3), 256, 0, stream>>>(gate, up, down, gatet, upt, downt);
  route_kernel<<<1, 256, 0, stream>>>(ids, T, hdr, src_of);
  gather_kernel<<<T, 256, 0, stream>>>(x, src_of, Xg);
  gemm1_kernel<<<dim3(maxt, EINTER / 64), 256, 0, stream>>>(Xg, gatet, upt, Hb, hdr, T);
  gemm2_kernel<<<dim3(maxt, HIDDEN / 128), 256, 0, stream>>>(Hb, downt, out, src_of, hdr, T);
}